// Round 3
// baseline (227.940 us; speedup 1.0000x reference)
//
#include <hip/hip_runtime.h>

// LSTMClassifier: B=4096, T=128, I=32, H=64, 2-layer LSTM + MLP head.
// Round 6: forced MFMA/VALU anti-phase via 2 barriers per timestep.
//   R3/R5 analysis: per SIMD (2 waves: one L0, one L1) wall=2250cyc/step,
//   VALU issue 1240 (mostly quarter-rate exp2/rcp), MFMA 450, idle 560 --
//   both waves hit MFMA-phase then eltwise-phase IN PHASE between barriers.
//   Fix: split each step into two barrier slots. L0: MFMA(k) in even slot,
//   eltwise+publish(k) in odd slot. L1 (lags 1.5 steps): MFMA(k-1) in ODD
//   slot, eltwise(k-2) in EVEN slot. Every slot = one group on the MFMA
//   pipe + one group on the VALU pipe; the barrier FORCES the anti-phase
//   (R5's counters gave slack but nothing forced it -> phase-locked).
//   All cross-wave LDS deps are barrier-separated (verified slot-by-slot;
//   double buffers suffice).
// Eltwise v2: biases folded into exp2 args; c-path fused to ONE rcp:
//   c = (c_prev*ds + (u-1)*df) * rcp(df*ds); rcp's paired across r
//   (1/a,1/b from one rcp(a*b)). 24 trans/wave-step, was 32. Ranges hard-
//   clamped: products <= ~2e31 << f32 max.
// f16 MFMA operands, fp32 accumulate/state. 256 blocks x 512 thr.

#define TT 128
#define II 32

typedef _Float16 half8 __attribute__((ext_vector_type(8)));
typedef float floatx4 __attribute__((ext_vector_type(4)));

#define LOG2E 1.4426950408889634f

__device__ __forceinline__ half8 cvt_frag(float4 a, float4 b) {
    half8 h;
    h[0] = (_Float16)a.x; h[1] = (_Float16)a.y; h[2] = (_Float16)a.z; h[3] = (_Float16)a.w;
    h[4] = (_Float16)b.x; h[5] = (_Float16)b.y; h[6] = (_Float16)b.z; h[7] = (_Float16)b.w;
    return h;
}

__device__ __forceinline__ half8 load_w_frag(const float* __restrict__ W, int n, int K, int k0) {
    const float* p = W + (size_t)n * K + k0;
    return cvt_frag(*(const float4*)p, *(const float4*)(p + 4));
}

// LSTM cell eltwise for the 4 accumulator rows, biases pre-folded.
//   sig(f+bf)              = 1/df,            df = 1 + exp2(nL*f + nbf)
//   sig(i+bi)*tanh(g+bg)   = (u-1)/ds,        ds = (1+vi)(u+1)
//   c = c_prev/df + (u-1)/ds = (c_prev*ds + (u-1)*df) * rcp(df*ds)
//   h = sig(o+bo)*tanh(c)  = (uc-1) * rcp((1+vo)(uc+1))
// Reciprocals paired across r: 1/a = rcp(a*b)*b, 1/b = rcp(a*b)*a.
// Ranges (hard clamps): u,uc <= 2^43.3, v's <= ~e^8 -> all pair products
// <= ~2e31 (f32 max 3.4e38); >= 1 (no underflow).
__device__ __forceinline__ void lstm_cell4(const floatx4* a, float* cr, float* hnew,
                                           float nbi, float nbf, float bg2, float nbo) {
    const float nL  = -LOG2E;
    const float p2L = 2.0f * LOG2E;
    const float C43 = 30.0f * LOG2E;   // |15 * 2L| clamp bound (post-scale)
    float m[4], numc[4];
    #pragma unroll
    for (int r = 0; r < 4; ++r) {
        float vf = __builtin_amdgcn_exp2f(fmaf(a[1][r], nL, nbf));
        float tg = __builtin_amdgcn_fmed3f(fmaf(a[2][r], p2L, bg2), -C43, C43);
        float u  = __builtin_amdgcn_exp2f(tg);
        float vi = __builtin_amdgcn_exp2f(fmaf(a[0][r], nL, nbi));
        float du = u + 1.0f;
        float ds = fmaf(vi, du, du);          // (1+vi)(u+1)
        float df = 1.0f + vf;
        m[r]    = df * ds;
        numc[r] = fmaf(cr[r], ds, (u - 1.0f) * df);
    }
    float p01 = m[0] * m[1], p23 = m[2] * m[3];
    float r01 = __builtin_amdgcn_rcpf(p01);
    float r23 = __builtin_amdgcn_rcpf(p23);
    float c0 = numc[0] * (r01 * m[1]);
    float c1 = numc[1] * (r01 * m[0]);
    float c2 = numc[2] * (r23 * m[3]);
    float c3 = numc[3] * (r23 * m[2]);
    float c[4] = {c0, c1, c2, c3};
    float dh[4], un[4];
    #pragma unroll
    for (int r = 0; r < 4; ++r) {
        cr[r] = c[r];
        float vo = __builtin_amdgcn_exp2f(fmaf(a[3][r], nL, nbo));
        float tc = __builtin_amdgcn_fmed3f(c[r] * p2L, -C43, C43);
        float uc = __builtin_amdgcn_exp2f(tc);
        float du2 = uc + 1.0f;
        dh[r] = fmaf(vo, du2, du2);           // (1+vo)(uc+1)
        un[r] = uc - 1.0f;
    }
    float q01 = dh[0] * dh[1], q23 = dh[2] * dh[3];
    float s01 = __builtin_amdgcn_rcpf(q01);
    float s23 = __builtin_amdgcn_rcpf(q23);
    hnew[0] = un[0] * (s01 * dh[1]);
    hnew[1] = un[1] * (s01 * dh[0]);
    hnew[2] = un[2] * (s23 * dh[3]);
    hnew[3] = un[3] * (s23 * dh[2]);
}

__global__ __launch_bounds__(512, 2) void lstm_fused(
    const float* __restrict__ x,
    const float* __restrict__ Wih0, const float* __restrict__ Whh0,
    const float* __restrict__ bih0, const float* __restrict__ bhh0,
    const float* __restrict__ Wih1, const float* __restrict__ Whh1,
    const float* __restrict__ bih1, const float* __restrict__ bhh1,
    const float* __restrict__ Wc1, const float* __restrict__ bc1,
    const float* __restrict__ Wc2, const float* __restrict__ bc2,
    float* __restrict__ out)
{
    // 72-f16 row stride (144B): b128 reads at free 2-way bank alias (m136).
    __shared__ __align__(16) _Float16 xs[2][16][40];
    __shared__ __align__(16) _Float16 h0s[2][16][72];
    __shared__ __align__(16) _Float16 h1s[2][16][72];
    __shared__ __align__(16) float h1f[16][68];
    __shared__ float hid[16][32];

    const int tid  = threadIdx.x;
    const int wid  = tid >> 6;
    const int w4   = wid & 3;
    const bool isL0 = (wid < 4);
    const int lane = tid & 63;
    const int q  = lane >> 4;
    const int lr = lane & 15;
    const int b0 = blockIdx.x * 16;

    const float nL  = -LOG2E;
    const float p2L = 2.0f * LOG2E;

    // ---- persistent weight fragments ----
    half8 bx0[4], bh0[4][2];
    half8 bi1[4][2], bh1[4][2];
    float bias[4];
    if (isL0) {
        #pragma unroll
        for (int g = 0; g < 4; ++g) {
            int n = (w4 + 4 * g) * 16 + lr;
            bx0[g]    = load_w_frag(Wih0, n, 32, q * 8);
            bh0[g][0] = load_w_frag(Whh0, n, 64, q * 8);
            bh0[g][1] = load_w_frag(Whh0, n, 64, 32 + q * 8);
            bias[g]   = bih0[n] + bhh0[n];
        }
    } else {
        #pragma unroll
        for (int g = 0; g < 4; ++g) {
            int n = (w4 + 4 * g) * 16 + lr;
            bi1[g][0] = load_w_frag(Wih1, n, 64, q * 8);
            bi1[g][1] = load_w_frag(Wih1, n, 64, 32 + q * 8);
            bh1[g][0] = load_w_frag(Whh1, n, 64, q * 8);
            bh1[g][1] = load_w_frag(Whh1, n, 64, 32 + q * 8);
            bias[g]   = bih1[n] + bhh1[n];
        }
    }
    const float nbi = nL * bias[0], nbf = nL * bias[1];
    const float bg2 = p2L * bias[2], nbo = nL * bias[3];
    const floatx4 zeroq = {0.f, 0.f, 0.f, 0.f};

    // zero-init both h buffers (h0(-1) = h1(-1) = 0)
    for (int i = tid; i < 2 * 16 * 72; i += 512) {
        ((_Float16*)h0s)[i] = (_Float16)0.0f;
        ((_Float16*)h1s)[i] = (_Float16)0.0f;
    }

    // x staging (L0 waves): thread -> (row xm, 2 consecutive floats)
    const int xm = (tid >> 4) & 15;
    const int xf = (tid & 15) * 2;
    const float* xrow = x + ((size_t)(b0 + xm) * TT) * II + xf;
    float2 xbuf = {0.f, 0.f};
    if (isL0) {
        float2 x0 = *(const float2*)(xrow);            // x(0) -> xs[0]
        xs[0][xm][xf]     = (_Float16)x0.x;
        xs[0][xm][xf + 1] = (_Float16)x0.y;
        xbuf = *(const float2*)(xrow + II);            // x(1) in regs
    }

    float cr[4] = {0.f, 0.f, 0.f, 0.f};
    float hnew[4];
    floatx4 a0[4];     // L0 gates: produced even slot, consumed odd slot
    floatx4 a1[4];     // L1 gates: produced odd slot, consumed next even slot

    // Slot schedule (iter k, slots 2k / 2k+1):
    //   even: L0 MFMA(k)        | L1 eltwise(k-2) -> h1s[k&1] (or h1f)
    //   odd : L0 eltwise(k)->h0s[k&1], stage x(k+1) | L1 MFMA(k-1) reads
    //         h0s[(k-1)&1], h1s[k&1]
    // Every cross-wave read refers to data published before the previous
    // barrier; same-slot accesses touch disjoint buffers.
    for (int k = 0; k < TT + 2; ++k) {
        __syncthreads();                         // ---- even slot ----
        const bool l0k = isL0 && (k < TT);
        float2 xnew = xbuf;
        if (l0k) {
            half8 xfrag = *(const half8*)&xs[k & 1][lr][q * 8];
            half8 h0a   = *(const half8*)&h0s[(k + 1) & 1][lr][q * 8];
            half8 h0b   = *(const half8*)&h0s[(k + 1) & 1][lr][32 + q * 8];
            if (k + 2 < TT) xnew = *(const float2*)(xrow + (size_t)(k + 2) * II);
            #pragma unroll
            for (int g = 0; g < 4; ++g) {
                floatx4 acc = __builtin_amdgcn_mfma_f32_16x16x32_f16(xfrag, bx0[g],    zeroq, 0, 0, 0);
                acc         = __builtin_amdgcn_mfma_f32_16x16x32_f16(h0a,   bh0[g][0], acc,   0, 0, 0);
                a0[g]       = __builtin_amdgcn_mfma_f32_16x16x32_f16(h0b,   bh0[g][1], acc,   0, 0, 0);
            }
        }
        if (!isL0 && k >= 2) {                   // L1 eltwise(k-2)
            lstm_cell4(a1, cr, hnew, nbi, nbf, bg2, nbo);
            if (k - 2 == TT - 1) {
                #pragma unroll
                for (int r = 0; r < 4; ++r)
                    h1f[q * 4 + r][w4 * 16 + lr] = hnew[r];
            } else {
                #pragma unroll
                for (int r = 0; r < 4; ++r)
                    h1s[k & 1][q * 4 + r][w4 * 16 + lr] = (_Float16)hnew[r];
            }
        }

        __syncthreads();                         // ---- odd slot ----
        if (l0k) {
            lstm_cell4(a0, cr, hnew, nbi, nbf, bg2, nbo);
            #pragma unroll
            for (int r = 0; r < 4; ++r)
                h0s[k & 1][q * 4 + r][w4 * 16 + lr] = (_Float16)hnew[r];
            if (k + 1 < TT) {                    // stage x(k+1) -> xs[(k+1)&1]
                xs[(k + 1) & 1][xm][xf]     = (_Float16)xbuf.x;
                xs[(k + 1) & 1][xm][xf + 1] = (_Float16)xbuf.y;
            }
            xbuf = xnew;
        }
        if (!isL0 && k >= 1 && k <= TT) {        // L1 MFMA(k-1)
            half8 g0a = *(const half8*)&h0s[(k - 1) & 1][lr][q * 8];
            half8 g0b = *(const half8*)&h0s[(k - 1) & 1][lr][32 + q * 8];
            half8 h1a = *(const half8*)&h1s[k & 1][lr][q * 8];
            half8 h1b = *(const half8*)&h1s[k & 1][lr][32 + q * 8];
            #pragma unroll
            for (int g = 0; g < 4; ++g) {
                floatx4 acc = __builtin_amdgcn_mfma_f32_16x16x32_f16(g0a, bi1[g][0], zeroq, 0, 0, 0);
                acc         = __builtin_amdgcn_mfma_f32_16x16x32_f16(g0b, bi1[g][1], acc,   0, 0, 0);
                acc         = __builtin_amdgcn_mfma_f32_16x16x32_f16(h1a, bh1[g][0], acc,   0, 0, 0);
                a1[g]       = __builtin_amdgcn_mfma_f32_16x16x32_f16(h1b, bh1[g][1], acc,   0, 0, 0);
            }
        }
    }
    __syncthreads();

    // ---- classifier (fp32) ----
    if (tid < 256) {
        int m = tid >> 4;
        int u = (tid & 15) * 2;
        float aa = bc1[u], bb = bc1[u + 1];
        const float* w0 = Wc1 + u * 64;
        const float* w1 = Wc1 + (u + 1) * 64;
        #pragma unroll 8
        for (int kk = 0; kk < 64; ++kk) {
            float hv = h1f[m][kk];
            aa += hv * w0[kk];
            bb += hv * w1[kk];
        }
        hid[m][u]     = fmaxf(aa, 0.f);
        hid[m][u + 1] = fmaxf(bb, 0.f);
    }
    __syncthreads();
    if (tid < 16) {
        float o = bc2[0];
        #pragma unroll
        for (int u = 0; u < 32; ++u) o += hid[tid][u] * Wc2[u];
        out[b0 + tid] = o;
    }
}

extern "C" void kernel_launch(void* const* d_in, const int* in_sizes, int n_in,
                              void* d_out, int out_size, void* d_ws, size_t ws_size,
                              hipStream_t stream) {
    (void)in_sizes; (void)n_in; (void)d_ws; (void)ws_size; (void)out_size;
    const float* x    = (const float*)d_in[0];
    const float* Wih0 = (const float*)d_in[1];
    const float* Whh0 = (const float*)d_in[2];
    const float* bih0 = (const float*)d_in[3];
    const float* bhh0 = (const float*)d_in[4];
    const float* Wih1 = (const float*)d_in[5];
    const float* Whh1 = (const float*)d_in[6];
    const float* bih1 = (const float*)d_in[7];
    const float* bhh1 = (const float*)d_in[8];
    const float* Wc1  = (const float*)d_in[9];
    const float* bc1  = (const float*)d_in[10];
    const float* Wc2  = (const float*)d_in[11];
    const float* bc2  = (const float*)d_in[12];
    lstm_fused<<<dim3(256), dim3(512), 0, stream>>>(
        x, Wih0, Whh0, bih0, bhh0, Wih1, Whh1, bih1, bhh1, Wc1, bc1, Wc2, bc2,
        (float*)d_out);
}

// Round 4
// 202.895 us; speedup vs baseline: 1.1234x; 1.1234x over previous
//
#include <hip/hip_runtime.h>

// LSTMClassifier: B=4096, T=128, I=32, H=64, 2-layer LSTM + MLP head.
// Round 7: consolidation. Three structural experiments (R4 reg-x, R5
// counter-decoupled groups, R6 two-slot anti-phase) ALL regressed vs the
// R3 single-barrier layer-pipelined structure (120us dispatch): at 2
// waves/SIMD every added sync costs more in convergence (~480cyc/barrier)
// than it buys in overlap. Total VALU issue is the invariant (~66us-equiv)
// and dominates. So: R3 structure EXACTLY (one barrier/step, LDS x-staging,
// double-buffered f16 h-state), with the numerically-validated VALU diet
// from R6 grafted on:
//  - fused eltwise cell: 24 trans/wave-step (was 32). c-path uses ONE rcp:
//    c = (c_prev*ds + (u-1)*df) * rcp(df*ds); reciprocals paired across r.
//  - biases folded into the exp2 args; MFMA chains start from a persistent
//    zero quad (no 16x v_mov acc-splat per step).
// f16 MFMA operands, fp32 accumulate/state. 256 blocks x 512 threads:
// waves 0-3 layer0 step k, waves 4-7 layer1 step k-1.

#define TT 128
#define II 32

typedef _Float16 half8 __attribute__((ext_vector_type(8)));
typedef float floatx4 __attribute__((ext_vector_type(4)));

#define LOG2E 1.4426950408889634f

__device__ __forceinline__ half8 cvt_frag(float4 a, float4 b) {
    half8 h;
    h[0] = (_Float16)a.x; h[1] = (_Float16)a.y; h[2] = (_Float16)a.z; h[3] = (_Float16)a.w;
    h[4] = (_Float16)b.x; h[5] = (_Float16)b.y; h[6] = (_Float16)b.z; h[7] = (_Float16)b.w;
    return h;
}

// Load 8 consecutive fp32 of row n (K-major) as an f16 MFMA B-fragment.
__device__ __forceinline__ half8 load_w_frag(const float* __restrict__ W, int n, int K, int k0) {
    const float* p = W + (size_t)n * K + k0;
    return cvt_frag(*(const float4*)p, *(const float4*)(p + 4));
}

// LSTM cell eltwise for the 4 accumulator rows, biases pre-folded
// (validated in R6: absmax unchanged at 2.44e-4):
//   sig(f+bf)             = 1/df,   df = 1 + exp2(nL*f + nbf)
//   sig(i+bi)*tanh(g+bg)  = (u-1)/ds,  ds = (1+vi)(u+1), u = e^{2(g+bg)} clamped
//   c = c_prev/df + (u-1)/ds = (c_prev*ds + (u-1)*df) * rcp(df*ds)
//   h = sig(o+bo)*tanh(c) = (uc-1) * rcp((1+vo)(uc+1))
// Reciprocals paired across r: 1/a = rcp(a*b)*b, 1/b = rcp(a*b)*a.
// Ranges: gates bounded (~|8|) in practice -> pair products <= ~1e27 << f32 max.
__device__ __forceinline__ void lstm_cell4(const floatx4* a, float* cr, float* hnew,
                                           float nbi, float nbf, float bg2, float nbo) {
    const float nL  = -LOG2E;
    const float p2L = 2.0f * LOG2E;
    const float C43 = 30.0f * LOG2E;   // |15 * 2L| clamp bound (post-scale)
    float m[4], numc[4];
    #pragma unroll
    for (int r = 0; r < 4; ++r) {
        float vf = __builtin_amdgcn_exp2f(fmaf(a[1][r], nL, nbf));
        float tg = __builtin_amdgcn_fmed3f(fmaf(a[2][r], p2L, bg2), -C43, C43);
        float u  = __builtin_amdgcn_exp2f(tg);
        float vi = __builtin_amdgcn_exp2f(fmaf(a[0][r], nL, nbi));
        float du = u + 1.0f;
        float ds = fmaf(vi, du, du);          // (1+vi)(u+1)
        float df = 1.0f + vf;
        m[r]    = df * ds;
        numc[r] = fmaf(cr[r], ds, (u - 1.0f) * df);
    }
    float r01 = __builtin_amdgcn_rcpf(m[0] * m[1]);
    float r23 = __builtin_amdgcn_rcpf(m[2] * m[3]);
    float c[4];
    c[0] = numc[0] * (r01 * m[1]);
    c[1] = numc[1] * (r01 * m[0]);
    c[2] = numc[2] * (r23 * m[3]);
    c[3] = numc[3] * (r23 * m[2]);
    float dh[4], un[4];
    #pragma unroll
    for (int r = 0; r < 4; ++r) {
        cr[r] = c[r];
        float vo = __builtin_amdgcn_exp2f(fmaf(a[3][r], nL, nbo));
        float tc = __builtin_amdgcn_fmed3f(c[r] * p2L, -C43, C43);
        float uc = __builtin_amdgcn_exp2f(tc);
        float du2 = uc + 1.0f;
        dh[r] = fmaf(vo, du2, du2);           // (1+vo)(uc+1)
        un[r] = uc - 1.0f;
    }
    float s01 = __builtin_amdgcn_rcpf(dh[0] * dh[1]);
    float s23 = __builtin_amdgcn_rcpf(dh[2] * dh[3]);
    hnew[0] = un[0] * (s01 * dh[1]);
    hnew[1] = un[1] * (s01 * dh[0]);
    hnew[2] = un[2] * (s23 * dh[3]);
    hnew[3] = un[3] * (s23 * dh[2]);
}

__global__ __launch_bounds__(512, 2) void lstm_fused(
    const float* __restrict__ x,
    const float* __restrict__ Wih0, const float* __restrict__ Whh0,
    const float* __restrict__ bih0, const float* __restrict__ bhh0,
    const float* __restrict__ Wih1, const float* __restrict__ Whh1,
    const float* __restrict__ bih1, const float* __restrict__ bhh1,
    const float* __restrict__ Wc1, const float* __restrict__ bc1,
    const float* __restrict__ Wc2, const float* __restrict__ bc2,
    float* __restrict__ out)
{
    // 72-f16 row stride (144B): b128 reads at free 2-way bank alias (m136).
    __shared__ __align__(16) _Float16 xs[2][16][40];
    __shared__ __align__(16) _Float16 h0s[2][16][72];
    __shared__ __align__(16) _Float16 h1s[2][16][72];
    __shared__ __align__(16) float h1f[16][68];   // final-step h1 (fp32)
    __shared__ float hid[16][32];

    const int tid  = threadIdx.x;
    const int wid  = tid >> 6;        // wave 0..7
    const int w4   = wid & 3;         // channel-group within the layer
    const bool isL0 = (wid < 4);
    const int lane = tid & 63;
    const int q  = lane >> 4;         // quad 0..3
    const int lr = lane & 15;
    const int b0 = blockIdx.x * 16;

    const float nL  = -LOG2E;
    const float p2L = 2.0f * LOG2E;

    // ---- persistent weight fragments (registers, whole kernel) ----
    // Wave group w4 owns gate-column tiles n = (w4 + 4g)*16: all four gates
    // for channels [16*w4, 16*w4+16) are lane-local at eltwise.
    half8 bx0[4], bh0[4][2];          // layer-0 waves
    half8 bi1[4][2], bh1[4][2];       // layer-1 waves
    float bias[4];
    if (isL0) {
        #pragma unroll
        for (int g = 0; g < 4; ++g) {
            int n = (w4 + 4 * g) * 16 + lr;
            bx0[g]    = load_w_frag(Wih0, n, 32, q * 8);
            bh0[g][0] = load_w_frag(Whh0, n, 64, q * 8);
            bh0[g][1] = load_w_frag(Whh0, n, 64, 32 + q * 8);
            bias[g]   = bih0[n] + bhh0[n];
        }
    } else {
        #pragma unroll
        for (int g = 0; g < 4; ++g) {
            int n = (w4 + 4 * g) * 16 + lr;
            bi1[g][0] = load_w_frag(Wih1, n, 64, q * 8);
            bi1[g][1] = load_w_frag(Wih1, n, 64, 32 + q * 8);
            bh1[g][0] = load_w_frag(Whh1, n, 64, q * 8);
            bh1[g][1] = load_w_frag(Whh1, n, 64, 32 + q * 8);
            bias[g]   = bih1[n] + bhh1[n];
        }
    }
    const float nbi = nL * bias[0], nbf = nL * bias[1];
    const float bg2 = p2L * bias[2], nbo = nL * bias[3];
    const floatx4 zeroq = {0.f, 0.f, 0.f, 0.f};

    // zero-init both h-state buffers (h0(-1) = h1(-1) = 0)
    for (int i = tid; i < 2 * 16 * 72; i += 512) {
        ((_Float16*)h0s)[i] = (_Float16)0.0f;
        ((_Float16*)h1s)[i] = (_Float16)0.0f;
    }

    // x staging (layer-0 waves only): thread -> (row xm, 2 consecutive floats)
    const int xm = (tid >> 4) & 15;
    const int xf = (tid & 15) * 2;
    const float* xrow = x + ((size_t)(b0 + xm) * TT) * II + xf;
    float2 xbuf = {0.f, 0.f};
    if (isL0) {
        float2 x0 = *(const float2*)(xrow);            // x(0) -> xs[0]
        xs[0][xm][xf]     = (_Float16)x0.x;
        xs[0][xm][xf + 1] = (_Float16)x0.y;
        if (TT > 1) xbuf = *(const float2*)(xrow + 1 * II);  // x(1) in regs
    }

    float cr[4] = {0.f, 0.f, 0.f, 0.f};   // c state for this wave's layer

    // Iteration k: waves 0-3 compute h0(k) (k < TT); waves 4-7 compute h1(k-1)
    // (k >= 1). h*(k) is written to buf[k&1]; iter k reads h*(k-1) from
    // buf[(k+1)&1]. x(k) lives in xs[k&1], staged during iter k-1.
    // Single barrier per iter: read-buffer and write-buffer never alias, and
    // writes to a buffer are separated from its readers by the barrier.
    for (int k = 0; k <= TT; ++k) {
        __syncthreads();

        const int rd = (k + 1) & 1;
        const int wr = k & 1;
        const bool doL0 = isL0 && (k < TT);
        const bool doL1 = (!isL0) && (k >= 1);
        floatx4 a[4];
        float hnew[4];
        float2 xnew = xbuf;

        if (doL0) {
            // gates(raw) = x(k) Wih0^T + h0(k-1) Whh0^T  (bias folded in cell)
            half8 xfrag = *(const half8*)&xs[wr][lr][q * 8];      // x(k) in xs[k&1]
            half8 h0a   = *(const half8*)&h0s[rd][lr][q * 8];
            half8 h0b   = *(const half8*)&h0s[rd][lr][32 + q * 8];
            if (k + 2 < TT) xnew = *(const float2*)(xrow + (size_t)(k + 2) * II);
            #pragma unroll
            for (int g = 0; g < 4; ++g) {
                floatx4 acc = __builtin_amdgcn_mfma_f32_16x16x32_f16(xfrag, bx0[g],    zeroq, 0, 0, 0);
                acc         = __builtin_amdgcn_mfma_f32_16x16x32_f16(h0a,   bh0[g][0], acc,   0, 0, 0);
                a[g]        = __builtin_amdgcn_mfma_f32_16x16x32_f16(h0b,   bh0[g][1], acc,   0, 0, 0);
            }
            lstm_cell4(a, cr, hnew, nbi, nbf, bg2, nbo);
        }
        if (doL1) {
            // gates(raw) = h0(k-1) Wih1^T + h1(k-2) Whh1^T
            half8 g0a = *(const half8*)&h0s[rd][lr][q * 8];
            half8 g0b = *(const half8*)&h0s[rd][lr][32 + q * 8];
            half8 h1a = *(const half8*)&h1s[rd][lr][q * 8];
            half8 h1b = *(const half8*)&h1s[rd][lr][32 + q * 8];
            #pragma unroll
            for (int g = 0; g < 4; ++g) {
                floatx4 acc = __builtin_amdgcn_mfma_f32_16x16x32_f16(g0a, bi1[g][0], zeroq, 0, 0, 0);
                acc         = __builtin_amdgcn_mfma_f32_16x16x32_f16(g0b, bi1[g][1], acc,   0, 0, 0);
                acc         = __builtin_amdgcn_mfma_f32_16x16x32_f16(h1a, bh1[g][0], acc,   0, 0, 0);
                a[g]        = __builtin_amdgcn_mfma_f32_16x16x32_f16(h1b, bh1[g][1], acc,   0, 0, 0);
            }
            lstm_cell4(a, cr, hnew, nbi, nbf, bg2, nbo);
        }

        // writes go to buf[wr]; readers of buf[wr] are past the next barrier
        if (doL0) {
            #pragma unroll
            for (int r = 0; r < 4; ++r)
                h0s[wr][q * 4 + r][w4 * 16 + lr] = (_Float16)hnew[r];
            if (k + 1 < TT) {                       // stage x(k+1) -> xs[(k+1)&1]
                xs[rd][xm][xf]     = (_Float16)xbuf.x;
                xs[rd][xm][xf + 1] = (_Float16)xbuf.y;
            }
            xbuf = xnew;
        }
        if (doL1) {
            if (k == TT) {
                #pragma unroll
                for (int r = 0; r < 4; ++r)
                    h1f[q * 4 + r][w4 * 16 + lr] = hnew[r];
            } else {
                #pragma unroll
                for (int r = 0; r < 4; ++r)
                    h1s[wr][q * 4 + r][w4 * 16 + lr] = (_Float16)hnew[r];
            }
        }
    }
    __syncthreads();

    // ---- classifier (fp32): hidden = relu(hT Wc1^T + bc1); out = hidden Wc2^T + bc2
    if (tid < 256) {
        int m = tid >> 4;
        int u = (tid & 15) * 2;
        float aa = bc1[u], bb = bc1[u + 1];
        const float* w0 = Wc1 + u * 64;
        const float* w1 = Wc1 + (u + 1) * 64;
        #pragma unroll 8
        for (int kk = 0; kk < 64; ++kk) {
            float hv = h1f[m][kk];
            aa += hv * w0[kk];
            bb += hv * w1[kk];
        }
        hid[m][u]     = fmaxf(aa, 0.f);
        hid[m][u + 1] = fmaxf(bb, 0.f);
    }
    __syncthreads();
    if (tid < 16) {
        float o = bc2[0];
        #pragma unroll
        for (int u = 0; u < 32; ++u) o += hid[tid][u] * Wc2[u];
        out[b0 + tid] = o;
    }
}

extern "C" void kernel_launch(void* const* d_in, const int* in_sizes, int n_in,
                              void* d_out, int out_size, void* d_ws, size_t ws_size,
                              hipStream_t stream) {
    (void)in_sizes; (void)n_in; (void)d_ws; (void)ws_size; (void)out_size;
    const float* x    = (const float*)d_in[0];
    const float* Wih0 = (const float*)d_in[1];
    const float* Whh0 = (const float*)d_in[2];
    const float* bih0 = (const float*)d_in[3];
    const float* bhh0 = (const float*)d_in[4];
    const float* Wih1 = (const float*)d_in[5];
    const float* Whh1 = (const float*)d_in[6];
    const float* bih1 = (const float*)d_in[7];
    const float* bhh1 = (const float*)d_in[8];
    const float* Wc1  = (const float*)d_in[9];
    const float* bc1  = (const float*)d_in[10];
    const float* Wc2  = (const float*)d_in[11];
    const float* bc2  = (const float*)d_in[12];
    lstm_fused<<<dim3(256), dim3(512), 0, stream>>>(
        x, Wih0, Whh0, bih0, bhh0, Wih1, Whh1, bih1, bhh1, Wc1, bc1, Wc2, bc2,
        (float*)d_out);
}